// Round 5
// baseline (721944.922 us; speedup 1.0000x reference)
//
#include <hip/hip_runtime.h>
#include <math.h>

#define Bn 128
#define Tn 256
#define Un 1024
#define Ln 256
#define Vn 512
#define G4 4096
#define KT 32
#define APAD 36

struct StepArgs {
  const float* ain[3]; const float* hin[3];
  const float* Wx[3];  const float* Wh[3];
  long astr[3]; int Dx[3]; int K[3];
};
struct GateArgs {
  const float* bias[3]; const float* zextra[3];
  float* cst[3]; float* hout[3]; float* hist[3];
};

// ---------------- embedding gather ----------------
__global__ void k_embed(const int* __restrict__ tok, const float* __restrict__ emb,
                        float* __restrict__ x) {
  int bt = blockIdx.x;
  int t = tok[bt];
  const float4* s = (const float4*)(emb + (long)t * Vn);
  float4* d = (float4*)(x + (long)bt * Vn);
  d[threadIdx.x] = s[threadIdx.x];
}

// ---------------- fused diagonal LSTM GEMM ----------------
// Per block: 64 rows x 128 z-cols, K/4 slice. Thread tile 4x8 (4 cols + 4 cols at +64).
// grid: x=32 colb, y=2 rowb, z=pos*4+ks
__global__ __launch_bounds__(256, 3) void k_lstm_gemm(StepArgs sa, float* __restrict__ zpart) {
  __shared__ float As[2][64][APAD];
  __shared__ float Ws[2][KT][128];
  int tid = threadIdx.x;
  int cb = blockIdx.x, rb = blockIdx.y;
  int pos = blockIdx.z >> 2, ks = blockIdx.z & 3;
  const float* ain = sa.ain[pos]; const float* hin = sa.hin[pos];
  const float* Wx = sa.Wx[pos];   const float* Wh = sa.Wh[pos];
  long astr = sa.astr[pos]; int Dx = sa.Dx[pos];
  int Kq = sa.K[pos] >> 2;
  int kbase = ks * Kq;
  int nch = Kq >> 5;                       // 12 or 16 chunks

  int ar = tid >> 3, akseg = (tid & 7) * 4;   // A loader: rows ar, ar+32
  int wr = tid >> 5, wcol = (tid & 31) * 4;   // W loader: rows wr,+8,+16,+24
  long arow0 = (long)rb * 64 + ar;
  int tr = tid >> 4, tc = tid & 15;
  int wc0 = cb * 128;

  float acc[4][8];
  #pragma unroll
  for (int i = 0; i < 4; ++i)
    #pragma unroll
    for (int j = 0; j < 8; ++j) acc[i][j] = 0.f;

  float4 pa0, pa1, pw0, pw1, pw2, pw3;

#define STAGE(CH) {                                                        \
    int k0 = kbase + (CH) * KT;                                            \
    const float* src; long rs; int ko;                                     \
    if (k0 < Dx) { src = ain; rs = astr; ko = k0; }                        \
    else         { src = hin; rs = Un;   ko = k0 - Dx; }                   \
    const float* p = src + arow0 * rs + ko + akseg;                        \
    pa0 = *(const float4*)p;                                               \
    pa1 = *(const float4*)(p + 32 * rs);                                   \
    const float* wsrc = (k0 < Dx) ? (Wx + (long)k0 * G4)                   \
                                  : (Wh + (long)(k0 - Dx) * G4);           \
    const float* q = wsrc + (long)wr * G4 + wc0 + wcol;                    \
    pw0 = *(const float4*)(q);                                             \
    pw1 = *(const float4*)(q + 8L * G4);                                   \
    pw2 = *(const float4*)(q + 16L * G4);                                  \
    pw3 = *(const float4*)(q + 24L * G4);                                  \
  }
#define COMMIT(BUF) {                                                      \
    *(float4*)&As[BUF][ar][akseg]      = pa0;                              \
    *(float4*)&As[BUF][ar + 32][akseg] = pa1;                              \
    *(float4*)&Ws[BUF][wr][wcol]       = pw0;                              \
    *(float4*)&Ws[BUF][wr + 8][wcol]   = pw1;                              \
    *(float4*)&Ws[BUF][wr + 16][wcol]  = pw2;                              \
    *(float4*)&Ws[BUF][wr + 24][wcol]  = pw3;                              \
  }

  STAGE(0); COMMIT(0);
  __syncthreads();

  for (int ch = 0; ch < nch; ++ch) {
    int buf = ch & 1;
    if (ch + 1 < nch) STAGE(ch + 1);
    #pragma unroll
    for (int kk = 0; kk < KT; kk += 4) {
      float4 a[4];
      #pragma unroll
      for (int r = 0; r < 4; ++r) a[r] = *(const float4*)&As[buf][tr * 4 + r][kk];
      #pragma unroll
      for (int q = 0; q < 4; ++q) {
        float4 w0 = *(const float4*)&Ws[buf][kk + q][tc * 4];
        float4 w1 = *(const float4*)&Ws[buf][kk + q][64 + tc * 4];
        #pragma unroll
        for (int r = 0; r < 4; ++r) {
          float av = (q == 0) ? a[r].x : (q == 1) ? a[r].y : (q == 2) ? a[r].z : a[r].w;
          acc[r][0] = fmaf(av, w0.x, acc[r][0]);
          acc[r][1] = fmaf(av, w0.y, acc[r][1]);
          acc[r][2] = fmaf(av, w0.z, acc[r][2]);
          acc[r][3] = fmaf(av, w0.w, acc[r][3]);
          acc[r][4] = fmaf(av, w1.x, acc[r][4]);
          acc[r][5] = fmaf(av, w1.y, acc[r][5]);
          acc[r][6] = fmaf(av, w1.z, acc[r][6]);
          acc[r][7] = fmaf(av, w1.w, acc[r][7]);
        }
      }
    }
    if (ch + 1 < nch) COMMIT((ch + 1) & 1);
    __syncthreads();
  }
#undef STAGE
#undef COMMIT

  // epilogue: write partial z tile
  long zb = ((long)(pos * 4 + ks) * Bn) * G4;
  #pragma unroll
  for (int j = 0; j < 4; ++j) {
    long row = (long)rb * 64 + tr * 4 + j;
    long base = zb + row * G4 + wc0;
    *(float4*)&zpart[base + tc * 4]      = make_float4(acc[j][0], acc[j][1], acc[j][2], acc[j][3]);
    *(float4*)&zpart[base + 64 + tc * 4] = make_float4(acc[j][4], acc[j][5], acc[j][6], acc[j][7]);
  }
}

// ---------------- gates: z = sum(partials)+bias(+zextra) -> c,h  (float4/thread) ----------------
__global__ void k_gates(GateArgs ga, const float* __restrict__ zpart) {
  int l = blockIdx.y;
  int e = blockIdx.x * 256 + threadIdx.x;     // 0..32767
  int row = e >> 8;                           // 0..127
  int u = (e & 255) * 4;                      // 0..1020
  const float* bias = ga.bias[l];
  const float* zx = ga.zextra[l];
  float4 z[4];
  #pragma unroll
  for (int g = 0; g < 4; ++g) {
    long coff = (long)g * Un + u;
    float4 v = *(const float4*)&bias[coff];
    if (zx) {
      float4 e4 = *(const float4*)&zx[(long)row * G4 + coff];
      v.x += e4.x; v.y += e4.y; v.z += e4.z; v.w += e4.w;
    }
    #pragma unroll
    for (int ks = 0; ks < 4; ++ks) {
      float4 p4 = *(const float4*)&zpart[(((long)l * 4 + ks) * Bn + row) * G4 + coff];
      v.x += p4.x; v.y += p4.y; v.z += p4.z; v.w += p4.w;
    }
    z[g] = v;
  }
  long idx = (long)row * Un + u;
  float4 cold = *(const float4*)&ga.cst[l][idx];
  float cc[4] = {cold.x, cold.y, cold.z, cold.w};
  float hh[4];
  #pragma unroll
  for (int j = 0; j < 4; ++j) {
    float a0 = (j == 0) ? z[0].x : (j == 1) ? z[0].y : (j == 2) ? z[0].z : z[0].w;
    float a1 = (j == 0) ? z[1].x : (j == 1) ? z[1].y : (j == 2) ? z[1].z : z[1].w;
    float a2 = (j == 0) ? z[2].x : (j == 1) ? z[2].y : (j == 2) ? z[2].z : z[2].w;
    float a3 = (j == 0) ? z[3].x : (j == 1) ? z[3].y : (j == 2) ? z[3].z : z[3].w;
    float ig = 1.f / (1.f + expf(-a0));
    float fg = 1.f / (1.f + expf(-a1));
    float gg = tanhf(a2);
    float og = 1.f / (1.f + expf(-a3));
    float cn = fg * cc[j] + ig * gg;
    cc[j] = cn;
    hh[j] = og * tanhf(cn);
  }
  *(float4*)&ga.cst[l][idx]  = make_float4(cc[0], cc[1], cc[2], cc[3]);
  float4 h4 = make_float4(hh[0], hh[1], hh[2], hh[3]);
  *(float4*)&ga.hout[l][idx] = h4;
  if (ga.hist[l]) *(float4*)&ga.hist[l][idx] = h4;
}

// ---------------- mean/sigma -> latent ----------------
__global__ void k_meansig(const float* __restrict__ c3, const float* __restrict__ wm,
                          const float* __restrict__ bm, const float* __restrict__ wsg,
                          const float* __restrict__ bs, const float* __restrict__ eps,
                          float* __restrict__ latent) {
  int b = blockIdx.x;
  int l = threadIdx.x;
  __shared__ float cs[Un];
  for (int uu = threadIdx.x; uu < Un; uu += 256) cs[uu] = c3[(long)b * Un + uu];
  __syncthreads();
  float m = 0.f, s = 0.f;
  for (int uu = 0; uu < Un; ++uu) {
    float cv = cs[uu];
    m = fmaf(cv, wm[(long)uu * Ln + l], m);
    s = fmaf(cv, wsg[(long)uu * Ln + l], s);
  }
  m += bm[l]; s += bs[l];
  latent[(long)b * Ln + l] = m + expf(s * 0.5f) + eps[(long)b * Ln + l];
}

// ---------------- zlat = latent @ dec_Wx0[0:256,:] ----------------
__global__ void k_zlat(const float* __restrict__ latent, const float* __restrict__ Wx0,
                       float* __restrict__ zlat) {
  long idx = (long)blockIdx.x * 256 + threadIdx.x;
  int b = (int)(idx >> 12), cc = (int)(idx & 4095);
  const float* lrow = latent + (long)b * Ln;
  float s = 0.f;
  for (int l = 0; l < Ln; ++l) s = fmaf(lrow[l], Wx0[(long)l * G4 + cc], s);
  zlat[idx] = s;
}

// ---------------- batched logits GEMM: [2048,1024]@[1024,512] ----------------
__global__ __launch_bounds__(256, 2) void k_logits_batch(
    const float* __restrict__ hist, const float* __restrict__ w,
    const float* __restrict__ bias, float* __restrict__ outLogits, int tbase) {
  __shared__ float As[2][64][APAD];
  __shared__ float Ws[2][KT][64];
  int tid = threadIdx.x;
  int cb = blockIdx.x;                     // 8 col blocks of 64
  int rb = blockIdx.y;                     // 32 row blocks of 64
  int ar = tid >> 3, akseg = (tid & 7) * 4;
  int wr = tid >> 4, wcol = (tid & 15) * 4;   // rows wr, wr+16
  long arow0 = (long)rb * 64 + ar;
  int tr = tid >> 4, tc = tid & 15;
  int wc0 = cb * 64;
  float acc[4][4];
  #pragma unroll
  for (int i = 0; i < 4; ++i)
    #pragma unroll
    for (int j = 0; j < 4; ++j) acc[i][j] = 0.f;

  float4 pa0, pa1, pw0, pw1;
#define LSTAGE(CH) {                                                 \
    int k0 = (CH) * KT;                                              \
    const float* p = hist + arow0 * Un + k0 + akseg;                 \
    pa0 = *(const float4*)p;                                         \
    pa1 = *(const float4*)(p + 32 * Un);                             \
    const float* q = w + (long)(k0 + wr) * Vn + wc0 + wcol;          \
    pw0 = *(const float4*)(q);                                       \
    pw1 = *(const float4*)(q + 16L * Vn);                            \
  }
#define LCOMMIT(BUF) {                                               \
    *(float4*)&As[BUF][ar][akseg]      = pa0;                        \
    *(float4*)&As[BUF][ar + 32][akseg] = pa1;                        \
    *(float4*)&Ws[BUF][wr][wcol]       = pw0;                        \
    *(float4*)&Ws[BUF][wr + 16][wcol]  = pw1;                        \
  }
  LSTAGE(0); LCOMMIT(0);
  __syncthreads();
  for (int ch = 0; ch < 32; ++ch) {
    int buf = ch & 1;
    if (ch + 1 < 32) LSTAGE(ch + 1);
    #pragma unroll
    for (int kk = 0; kk < KT; kk += 4) {
      float4 a[4];
      #pragma unroll
      for (int r = 0; r < 4; ++r) a[r] = *(const float4*)&As[buf][tr * 4 + r][kk];
      #pragma unroll
      for (int q = 0; q < 4; ++q) {
        float4 wv = *(const float4*)&Ws[buf][kk + q][tc * 4];
        #pragma unroll
        for (int r = 0; r < 4; ++r) {
          float av = (q == 0) ? a[r].x : (q == 1) ? a[r].y : (q == 2) ? a[r].z : a[r].w;
          acc[r][0] = fmaf(av, wv.x, acc[r][0]);
          acc[r][1] = fmaf(av, wv.y, acc[r][1]);
          acc[r][2] = fmaf(av, wv.z, acc[r][2]);
          acc[r][3] = fmaf(av, wv.w, acc[r][3]);
        }
      }
    }
    if (ch + 1 < 32) LCOMMIT((ch + 1) & 1);
    __syncthreads();
  }
#undef LSTAGE
#undef LCOMMIT
  float4 bv = *(const float4*)&bias[wc0 + tc * 4];
  #pragma unroll
  for (int j = 0; j < 4; ++j) {
    int r = rb * 64 + tr * 4 + j;
    int tloc = r >> 7, b = r & 127;
    int t = tbase + tloc;
    long base = ((long)b * Tn + t) * Vn + wc0 + tc * 4;
    *(float4*)&outLogits[base] = make_float4(acc[j][0] + bv.x, acc[j][1] + bv.y,
                                             acc[j][2] + bv.z, acc[j][3] + bv.w);
  }
}

// ---------------- final argmax over logits ----------------
__global__ void k_argmax(const float* __restrict__ logits, float* __restrict__ outArg) {
  int row = blockIdx.x * 4 + (threadIdx.x >> 6);
  int lane = threadIdx.x & 63;
  const float* p = logits + (long)row * Vn;
  float best = -1e30f; int bi = 0;
  #pragma unroll
  for (int i = 0; i < 8; ++i) {
    int c = lane + i * 64;
    float v = p[c];
    if (v > best || (v == best && c < bi)) { best = v; bi = c; }
  }
  #pragma unroll
  for (int off = 32; off; off >>= 1) {
    float ov = __shfl_xor(best, off);
    int oi = __shfl_xor(bi, off);
    if (ov > best || (ov == best && oi < bi)) { best = ov; bi = oi; }
  }
  if (lane == 0) outArg[row] = (float)bi;
}

// ---------------- host ----------------
extern "C" void kernel_launch(void* const* d_in, const int* in_sizes, int n_in,
                              void* d_out, int out_size, void* d_ws, size_t ws_size,
                              hipStream_t stream) {
  (void)in_sizes; (void)n_in; (void)out_size; (void)ws_size;
  const int*   tokens = (const int*)d_in[0];
  const float* emb    = (const float*)d_in[1];
  const float* eWx[3] = {(const float*)d_in[2], (const float*)d_in[5], (const float*)d_in[8]};
  const float* eWh[3] = {(const float*)d_in[3], (const float*)d_in[6], (const float*)d_in[9]};
  const float* ebv[3] = {(const float*)d_in[4], (const float*)d_in[7], (const float*)d_in[10]};
  const float* dWx[3] = {(const float*)d_in[11], (const float*)d_in[14], (const float*)d_in[17]};
  const float* dWh[3] = {(const float*)d_in[12], (const float*)d_in[15], (const float*)d_in[18]};
  const float* dbv[3] = {(const float*)d_in[13], (const float*)d_in[16], (const float*)d_in[19]};
  const float* w_mean  = (const float*)d_in[20];
  const float* b_mean  = (const float*)d_in[21];
  const float* w_sigma = (const float*)d_in[22];
  const float* b_sigma = (const float*)d_in[23];
  const float* dec_w   = (const float*)d_in[24];
  const float* dec_b   = (const float*)d_in[25];
  const float* eps     = (const float*)d_in[26];
  float* out = (float*)d_out;
  float* outArg    = out;
  float* outLogits = out + (long)Bn * Tn;

  float* ws = (float*)d_ws;
  long off = 0;
  float* x      = ws + off; off += (long)Bn * Tn * Vn;
  float* hb     = ws + off; off += 12L * Bn * Un;
  float* cbuf   = ws + off; off += 6L * Bn * Un;
  float* latent = ws + off; off += (long)Bn * Ln;
  float* zlat   = ws + off; off += (long)Bn * G4;
  float* zpart  = ws + off; off += 12L * Bn * G4;
  float* hist   = ws + off; off += 16L * Bn * Un;

  #define HBUF(net, l, par) (hb + (((net) * 3 + (l)) * 2 + (par)) * (long)(Bn * Un))
  #define CBUF(net, l)      (cbuf + ((net) * 3 + (l)) * (long)(Bn * Un))

  k_embed<<<Bn * Tn, 128, 0, stream>>>(tokens, emb, x);
  hipMemsetAsync(hb, 0, 18L * Bn * Un * sizeof(float), stream);  // h + c

  for (int net = 0; net < 2; ++net) {
    for (int s = 0; s < Tn + 2; ++s) {
      StepArgs sa; GateArgs ga; int nl = 0;
      for (int l = 0; l < 3; ++l) {
        int t = s - l;
        if (t < 0 || t >= Tn) continue;
        int p = nl++;
        if (l == 0) {
          sa.ain[p] = x + (long)t * Vn; sa.astr[p] = (long)Tn * Vn;
          sa.Dx[p] = Vn; sa.K[p] = 1536;
          sa.Wx[p] = net ? (dWx[0] + (long)Ln * G4) : eWx[0];
        } else {
          sa.ain[p] = HBUF(net, l - 1, t & 1); sa.astr[p] = Un;
          sa.Dx[p] = Un; sa.K[p] = 2048;
          sa.Wx[p] = net ? dWx[l] : eWx[l];
        }
        sa.Wh[p]  = net ? dWh[l] : eWh[l];
        sa.hin[p] = HBUF(net, l, (t + 1) & 1);
        ga.bias[p]   = net ? dbv[l] : ebv[l];
        ga.zextra[p] = (net == 1 && l == 0) ? zlat : nullptr;
        ga.cst[p]    = CBUF(net, l);
        ga.hout[p]   = HBUF(net, l, t & 1);
        ga.hist[p]   = (net == 1 && l == 2) ? (hist + (long)(t & 15) * Bn * Un) : nullptr;
      }
      k_lstm_gemm<<<dim3(32, 2, nl * 4), 256, 0, stream>>>(sa, zpart);
      k_gates<<<dim3(128, nl), 256, 0, stream>>>(ga, zpart);
      if (net == 1) {
        int t2 = s - 2;
        if (t2 >= 0 && (t2 & 15) == 15)
          k_logits_batch<<<dim3(8, 32), 256, 0, stream>>>(hist, dec_w, dec_b, outLogits, t2 - 15);
      }
    }
    if (net == 0) {
      k_meansig<<<Bn, 256, 0, stream>>>(CBUF(0, 2), w_mean, b_mean, w_sigma, b_sigma, eps, latent);
      k_zlat<<<(Bn * G4) / 256, 256, 0, stream>>>(latent, dWx[0], zlat);
    }
  }
  k_argmax<<<(Bn * Tn) / 4, 256, 0, stream>>>(outLogits, outArg);
}